// Round 3
// baseline (402.390 us; speedup 1.0000x reference)
//
#include <hip/hip_runtime.h>

typedef unsigned short u16;
typedef short short8 __attribute__((ext_vector_type(8)));
typedef float f32x4 __attribute__((ext_vector_type(4)));

#define P_OUT 29791      // 31^3
#define PPAD  29824      // 233*128
#define NBAT  4
#define NCH   512
#define KDIM  128

// ---- fp32 -> bf16 (RNE) ----
__device__ __forceinline__ u16 f2bf(float f) {
  unsigned u = __builtin_bit_cast(unsigned, f);
  unsigned r = (u + 0x7fffu + ((u >> 16) & 1u)) >> 16;
  return (u16)r;
}
__device__ __forceinline__ unsigned pk2(float a, float b) {
  return (unsigned)f2bf(a) | ((unsigned)f2bf(b) << 16);
}

// ---- prep: x (4,16,32,32,32) -> yb bf16 [4][29824][128] + ysq fp32 ----
// row g = n*PPAD + p ; 16 lanes per row, lane c handles j = c*8 .. c*8+7
__global__ void prep_y_kernel(const float* __restrict__ x,
                              u16* __restrict__ yb, float* __restrict__ ysq) {
  const int tid = threadIdx.x;
  const int g = blockIdx.x * 16 + (tid >> 4);
  const int c = tid & 15;
  const int nb = g / PPAD;
  const int pp = g - nb * PPAD;
  float v[8];
  if (pp < P_OUT) {
    const int d = pp / 961;
    const int rem = pp - d * 961;
    const int h = rem / 31;
    const int w = rem - h * 31;
    const float* xb = x + (((size_t)nb * 16 + c) << 15) + d * 1024 + h * 32 + w;
    v[0] = xb[0];    v[1] = xb[1];
    v[2] = xb[32];   v[3] = xb[33];
    v[4] = xb[1024]; v[5] = xb[1025];
    v[6] = xb[1056]; v[7] = xb[1057];
  } else {
#pragma unroll
    for (int i = 0; i < 8; ++i) v[i] = 0.f;
  }
  float s = 0.f;
#pragma unroll
  for (int i = 0; i < 8; ++i) s += v[i] * v[i];
#pragma unroll
  for (int m = 1; m < 16; m <<= 1) s += __shfl_xor(s, m, 64);
  uint4 pk;
  pk.x = pk2(v[0], v[1]); pk.y = pk2(v[2], v[3]);
  pk.z = pk2(v[4], v[5]); pk.w = pk2(v[6], v[7]);
  *(uint4*)(yb + (size_t)g * 128 + c * 8) = pk;
  if (c == 0) ysq[g] = s;
}

// ---- prep: w (512,128) -> wb bf16 + wsq fp32 ----
__global__ void prep_w_kernel(const float* __restrict__ w,
                              u16* __restrict__ wb, float* __restrict__ wsq) {
  const int tid = threadIdx.x;
  const int g = blockIdx.x * 16 + (tid >> 4);  // 0..511
  const int c = tid & 15;
  const float4* wr = (const float4*)(w + g * 128 + c * 8);
  float4 f0 = wr[0], f1 = wr[1];
  float s = f0.x*f0.x + f0.y*f0.y + f0.z*f0.z + f0.w*f0.w
          + f1.x*f1.x + f1.y*f1.y + f1.z*f1.z + f1.w*f1.w;
#pragma unroll
  for (int m = 1; m < 16; m <<= 1) s += __shfl_xor(s, m, 64);
  uint4 pk;
  pk.x = pk2(f0.x, f0.y); pk.y = pk2(f0.z, f0.w);
  pk.z = pk2(f1.x, f1.y); pk.w = pk2(f1.z, f1.w);
  *(uint4*)(wb + g * 128 + c * 8) = pk;
  if (c == 0) wsq[g] = s;
}

// async global->LDS, 16 B per lane, lands at ldsbase + lane*16
#define GLDS(g, l) __builtin_amdgcn_global_load_lds(                         \
    (const __attribute__((address_space(1))) unsigned int*)(g),              \
    (__attribute__((address_space(3))) unsigned int*)(l), 16, 0, 0)

// ---- GEMM + epilogue: out[n][ch][p] = exp(-(ysq[p] - 2*y.w + wsq[ch])) ----
// Block owns a 128-p stripe x ALL 512 channels. y-tile (128 p x 128 k bf16,
// 32 KB) staged in LDS ONCE (chunk-of-16B position = chunk ^ (row&15));
// then ct-loop over 4 ch-tiles streams w-tiles (16 KB per BK=64 stage,
// chunk ^ (row&7)). yb is read exactly once from HBM/LLC.
__global__ void __launch_bounds__(256, 3)
gauss_gemm_kernel(const u16* __restrict__ yb,
                  const float* __restrict__ ysq,
                  const u16* __restrict__ wb,
                  const float* __restrict__ wsq,
                  float* __restrict__ out) {
  __shared__ __align__(16) u16 Bs[128 * 128];  // y tile  [p][k=128], 32 KB
  __shared__ __align__(16) u16 As[128 * 64];   // w stage [ch][k=64], 16 KB

  const int bid = blockIdx.x;
  const int pt = bid % 233;          // 233 p tiles
  const int nb = bid / 233;          // 4 batches
  const int p0 = pt * 128;

  const int tid = threadIdx.x;
  const int wid = tid >> 6;
  const int lane = tid & 63;
  const int quad = lane >> 4;
  const int col = lane & 15;
  const int wch = wid & 1;   // wave ch-half
  const int wp = wid >> 1;   // wave p-half

  // ---- stage B (y-tile) once: 2048 chunks of 16 B, 8 rounds ----
  const size_t ybase = ((size_t)nb * PPAD + p0) * 128;
#pragma unroll
  for (int t = 0; t < 8; ++t) {
    const int Lb = t * 256 + wid * 64;      // wave-uniform chunk base
    const int L = Lb + lane;
    const int row = L >> 4;                 // 16 chunks per 256 B row
    const int jc = (L & 15) ^ (row & 15);   // unswizzled k-chunk
    GLDS(yb + ybase + (size_t)row * 128 + jc * 8, &Bs[Lb * 8]);
  }

  // epilogue p indices / ysq (ct-independent)
  float ysv[4];
  int pj[4];
#pragma unroll
  for (int j = 0; j < 4; ++j) {
    pj[j] = p0 + wp * 64 + j * 16 + col;
    ysv[j] = ysq[(size_t)nb * PPAD + pj[j]];
  }
  const bool full = (p0 + 128 <= P_OUT);    // all but pt==232

  for (int ct = 0; ct < 4; ++ct) {
    const int c0 = ct * 128;

    f32x4 acc[4][4];
#pragma unroll
    for (int i = 0; i < 4; ++i)
#pragma unroll
      for (int j = 0; j < 4; ++j) acc[i][j] = (f32x4){0.f, 0.f, 0.f, 0.f};

#pragma unroll
    for (int it = 0; it < 2; ++it) {
      const int k0 = it * 64;
      // A stage: 16 KB (4 rounds of 256 lanes x 16 B)
#pragma unroll
      for (int t = 0; t < 4; ++t) {
        const int Lb = (wid * 4 + t) * 64;
        const int L = Lb + lane;
        const int row = L >> 3;               // 8 chunks per 128 B row
        const int jc = (L & 7) ^ (row & 7);
        GLDS(wb + (size_t)(c0 + row) * 128 + k0 + jc * 8, &As[Lb * 8]);
      }
      __syncthreads();   // drains B-stage (first time) + A-stage
#pragma unroll
      for (int ks = 0; ks < 2; ++ks) {
        short8 a[4], b[4];
#pragma unroll
        for (int i = 0; i < 4; ++i) {
          const int rowA = wch * 64 + i * 16 + col;
          const int ca = (ks * 4 + quad) ^ (rowA & 7);
          a[i] = *(const short8*)&As[rowA * 64 + ca * 8];
          const int rowB = wp * 64 + i * 16 + col;
          const int cb = (it * 8 + ks * 4 + quad) ^ (rowB & 15);
          b[i] = *(const short8*)&Bs[rowB * 128 + cb * 8];
        }
#pragma unroll
        for (int i = 0; i < 4; ++i)
#pragma unroll
          for (int j = 0; j < 4; ++j)
            acc[i][j] = __builtin_amdgcn_mfma_f32_16x16x32_bf16(a[i], b[j],
                                                                acc[i][j], 0, 0, 0);
      }
      __syncthreads();   // As read complete before next stage overwrites
    }

    // ---- epilogue for this ch-tile: out = exp(-(ysq - 2*cross + wsq)) ----
    if (full) {
#pragma unroll
      for (int i = 0; i < 4; ++i) {
#pragma unroll
        for (int r = 0; r < 4; ++r) {
          const int ch = c0 + wch * 64 + i * 16 + quad * 4 + r;
          const float wsv = wsq[ch];
          float* ob = out + ((size_t)(nb * NCH + ch)) * P_OUT;
#pragma unroll
          for (int j = 0; j < 4; ++j) {
            const float dist = ysv[j] - 2.f * acc[i][j][r] + wsv;
            __builtin_nontemporal_store(__expf(-dist), ob + pj[j]);
          }
        }
      }
    } else {
#pragma unroll
      for (int i = 0; i < 4; ++i) {
#pragma unroll
        for (int r = 0; r < 4; ++r) {
          const int ch = c0 + wch * 64 + i * 16 + quad * 4 + r;
          const float wsv = wsq[ch];
          float* ob = out + ((size_t)(nb * NCH + ch)) * P_OUT;
#pragma unroll
          for (int j = 0; j < 4; ++j) {
            if (pj[j] < P_OUT) {
              const float dist = ysv[j] - 2.f * acc[i][j][r] + wsv;
              __builtin_nontemporal_store(__expf(-dist), ob + pj[j]);
            }
          }
        }
      }
    }
  }
}

extern "C" void kernel_launch(void* const* d_in, const int* in_sizes, int n_in,
                              void* d_out, int out_size, void* d_ws, size_t ws_size,
                              hipStream_t stream) {
  const float* x = (const float*)d_in[0];
  const float* w = (const float*)d_in[1];
  float* out = (float*)d_out;
  char* ws = (char*)d_ws;
  // workspace layout (16B-aligned):
  u16* yb    = (u16*)ws;                     // 4*29824*128 bf16 = 61,079,552 B
  float* ysq = (float*)(ws + 61079552);      // 119,296 * 4     =    477,184 B
  u16* wb    = (u16*)(ws + 61556736);        // 512*128 bf16    =    131,072 B
  float* wsq = (float*)(ws + 61687808);      // 512*4           =      2,048 B

  prep_w_kernel<<<32, 256, 0, stream>>>(w, wb, wsq);     // 512 rows
  prep_y_kernel<<<7456, 256, 0, stream>>>(x, yb, ysq);   // 119,296 rows
  gauss_gemm_kernel<<<932, 256, 0, stream>>>(yb, ysq, wb, wsq, out);
}

// Round 4
// 340.401 us; speedup vs baseline: 1.1821x; 1.1821x over previous
//
#include <hip/hip_runtime.h>

typedef unsigned short u16;
typedef short short8 __attribute__((ext_vector_type(8)));
typedef float f32x4 __attribute__((ext_vector_type(4)));

#define P_OUT 29791      // 31^3
#define PPAD  29824      // 233*128
#define NBAT  4
#define NCH   512
#define KDIM  128

// ---- fp32 -> bf16 (RNE) ----
__device__ __forceinline__ u16 f2bf(float f) {
  unsigned u = __builtin_bit_cast(unsigned, f);
  unsigned r = (u + 0x7fffu + ((u >> 16) & 1u)) >> 16;
  return (u16)r;
}
__device__ __forceinline__ unsigned pk2(float a, float b) {
  return (unsigned)f2bf(a) | ((unsigned)f2bf(b) << 16);
}

// ---- prep: x (4,16,32,32,32) -> yb bf16 [4][29824][128] + ysq fp32 ----
// row g = n*PPAD + p ; 16 lanes per row, lane c handles j = c*8 .. c*8+7
__global__ void prep_y_kernel(const float* __restrict__ x,
                              u16* __restrict__ yb, float* __restrict__ ysq) {
  const int tid = threadIdx.x;
  const int g = blockIdx.x * 16 + (tid >> 4);
  const int c = tid & 15;
  const int nb = g / PPAD;
  const int pp = g - nb * PPAD;
  float v[8];
  if (pp < P_OUT) {
    const int d = pp / 961;
    const int rem = pp - d * 961;
    const int h = rem / 31;
    const int w = rem - h * 31;
    const float* xb = x + (((size_t)nb * 16 + c) << 15) + d * 1024 + h * 32 + w;
    v[0] = xb[0];    v[1] = xb[1];
    v[2] = xb[32];   v[3] = xb[33];
    v[4] = xb[1024]; v[5] = xb[1025];
    v[6] = xb[1056]; v[7] = xb[1057];
  } else {
#pragma unroll
    for (int i = 0; i < 8; ++i) v[i] = 0.f;
  }
  float s = 0.f;
#pragma unroll
  for (int i = 0; i < 8; ++i) s += v[i] * v[i];
#pragma unroll
  for (int m = 1; m < 16; m <<= 1) s += __shfl_xor(s, m, 64);
  uint4 pk;
  pk.x = pk2(v[0], v[1]); pk.y = pk2(v[2], v[3]);
  pk.z = pk2(v[4], v[5]); pk.w = pk2(v[6], v[7]);
  *(uint4*)(yb + (size_t)g * 128 + c * 8) = pk;
  if (c == 0) ysq[g] = s;
}

// ---- prep: w (512,128) -> wb bf16 + wsq fp32 ----
__global__ void prep_w_kernel(const float* __restrict__ w,
                              u16* __restrict__ wb, float* __restrict__ wsq) {
  const int tid = threadIdx.x;
  const int g = blockIdx.x * 16 + (tid >> 4);  // 0..511
  const int c = tid & 15;
  const float4* wr = (const float4*)(w + g * 128 + c * 8);
  float4 f0 = wr[0], f1 = wr[1];
  float s = f0.x*f0.x + f0.y*f0.y + f0.z*f0.z + f0.w*f0.w
          + f1.x*f1.x + f1.y*f1.y + f1.z*f1.z + f1.w*f1.w;
#pragma unroll
  for (int m = 1; m < 16; m <<= 1) s += __shfl_xor(s, m, 64);
  uint4 pk;
  pk.x = pk2(f0.x, f0.y); pk.y = pk2(f0.z, f0.w);
  pk.z = pk2(f1.x, f1.y); pk.w = pk2(f1.z, f1.w);
  *(uint4*)(wb + g * 128 + c * 8) = pk;
  if (c == 0) wsq[g] = s;
}

// async global->LDS, 16 B per lane, lands at ldsbase + lane*16
#define GLDS(g, l) __builtin_amdgcn_global_load_lds(                         \
    (const __attribute__((address_space(1))) unsigned int*)(g),              \
    (__attribute__((address_space(3))) unsigned int*)(l), 16, 0, 0)

// ---- GEMM + epilogue: out[n][ch][p] = exp(-(ysq[p] - 2*y.w + wsq[ch])) ----
// Tile: 128 p x 128 ch, K=128 in two BK=64 stages.
// Operand roles: A = y (m=p), B = w (n=ch)  =>  C/D: row=p (quad*4+reg),
// col=ch (lane&15). Each lane owns 4 CONSECUTIVE p of one ch row ->
// global_store_dwordx4 epilogue (16 B/lane).
// LDS layout: [row][8 chunks of 16B], chunk position = chunk ^ (row&7) so
// lane-linear global_load_lds staging and ds_read_b128 frag reads are both
// conflict-free.
__global__ void gauss_gemm_kernel(const u16* __restrict__ yb,
                                  const float* __restrict__ ysq,
                                  const u16* __restrict__ wb,
                                  const float* __restrict__ wsq,
                                  float* __restrict__ out) {
  __shared__ __align__(16) u16 Ys[128 * 64];  // y tile [p][k]
  __shared__ __align__(16) u16 Ws[128 * 64];  // w tile [ch][k]

  const int bid = blockIdx.x;
  const int ct = bid & 3;            // 4 ch tiles
  const int pt = (bid >> 2) % 233;   // 233 p tiles
  const int nb = bid / 932;          // 4 batches
  const int p0 = pt * 128;
  const int c0 = ct * 128;

  const int tid = threadIdx.x;
  const int wid = tid >> 6;
  const int lane = tid & 63;
  const int quad = lane >> 4;
  const int col = lane & 15;
  const int wp = wid & 1;    // wave p-half
  const int wch = wid >> 1;  // wave ch-half

  const size_t ybase = ((size_t)nb * PPAD + p0) * 128;

  f32x4 acc[4][4];           // [i: p-tile][j: ch-tile]
#pragma unroll
  for (int i = 0; i < 4; ++i)
#pragma unroll
    for (int j = 0; j < 4; ++j) acc[i][j] = (f32x4){0.f, 0.f, 0.f, 0.f};

#pragma unroll
  for (int it = 0; it < 2; ++it) {
    const int k0 = it * 64;
    if (it) __syncthreads();   // protect previous stage's LDS reads
    // stage: 16KB Y + 16KB W, 4 rounds of 256 lanes x 16 B each
#pragma unroll
    for (int t = 0; t < 4; ++t) {
      const int Lb = (wid * 4 + t) * 64;      // chunk base (wave-uniform)
      const int L = Lb + lane;
      const int row = L >> 3;
      const int jc = (L & 7) ^ (row & 7);     // unswizzled k-chunk
      GLDS(yb + ybase + (size_t)row * 128 + k0 + jc * 8, &Ys[Lb * 8]);
      GLDS(wb + (size_t)(c0 + row) * 128 + k0 + jc * 8, &Ws[Lb * 8]);
    }
    __syncthreads();
#pragma unroll
    for (int ks = 0; ks < 2; ++ks) {
      short8 a[4], b[4];
#pragma unroll
      for (int i = 0; i < 4; ++i) {
        const int rowY = wp * 64 + i * 16 + col;
        const int cy = (ks * 4 + quad) ^ (rowY & 7);
        a[i] = *(const short8*)&Ys[rowY * 64 + cy * 8];
        const int rowW = wch * 64 + i * 16 + col;
        const int cw = (ks * 4 + quad) ^ (rowW & 7);
        b[i] = *(const short8*)&Ws[rowW * 64 + cw * 8];
      }
#pragma unroll
      for (int i = 0; i < 4; ++i)
#pragma unroll
        for (int j = 0; j < 4; ++j)
          acc[i][j] = __builtin_amdgcn_mfma_f32_16x16x32_bf16(a[i], b[j],
                                                              acc[i][j], 0, 0, 0);
    }
  }
  // no trailing barrier: stores below are fire-and-forget to kernel end

  // epilogue: dist = ysq[p] - 2*cross + wsq[ch] ; out = exp(-dist)
  const bool full = (p0 + 128 <= P_OUT);   // all but pt==232
  int pi[4];
  float4 ysv[4];
#pragma unroll
  for (int i = 0; i < 4; ++i) {
    pi[i] = p0 + wp * 64 + i * 16 + quad * 4;
    ysv[i] = *(const float4*)(ysq + (size_t)nb * PPAD + pi[i]);
  }
#pragma unroll
  for (int j = 0; j < 4; ++j) {
    const int ch = c0 + wch * 64 + j * 16 + col;
    const float wsv = wsq[ch];
    float* ob = out + ((size_t)(nb * NCH + ch)) * P_OUT;
    if (full) {
#pragma unroll
      for (int i = 0; i < 4; ++i) {
        float4 o;
        o.x = __expf(-(ysv[i].x - 2.f * acc[i][j][0] + wsv));
        o.y = __expf(-(ysv[i].y - 2.f * acc[i][j][1] + wsv));
        o.z = __expf(-(ysv[i].z - 2.f * acc[i][j][2] + wsv));
        o.w = __expf(-(ysv[i].w - 2.f * acc[i][j][3] + wsv));
        *(float4*)(ob + pi[i]) = o;   // 4B-aligned dwordx4 is fine on gfx9+
      }
    } else {
#pragma unroll
      for (int i = 0; i < 4; ++i) {
        const float yv[4] = {ysv[i].x, ysv[i].y, ysv[i].z, ysv[i].w};
#pragma unroll
        for (int r = 0; r < 4; ++r) {
          const int p = pi[i] + r;
          if (p < P_OUT)
            ob[p] = __expf(-(yv[r] - 2.f * acc[i][j][r] + wsv));
        }
      }
    }
  }
}

extern "C" void kernel_launch(void* const* d_in, const int* in_sizes, int n_in,
                              void* d_out, int out_size, void* d_ws, size_t ws_size,
                              hipStream_t stream) {
  const float* x = (const float*)d_in[0];
  const float* w = (const float*)d_in[1];
  float* out = (float*)d_out;
  char* ws = (char*)d_ws;
  // workspace layout (16B-aligned):
  u16* yb    = (u16*)ws;                     // 4*29824*128 bf16 = 61,079,552 B
  float* ysq = (float*)(ws + 61079552);      // 119,296 * 4     =    477,184 B
  u16* wb    = (u16*)(ws + 61556736);        // 512*128 bf16    =    131,072 B
  float* wsq = (float*)(ws + 61687808);      // 512*4           =      2,048 B

  prep_w_kernel<<<32, 256, 0, stream>>>(w, wb, wsq);     // 512 rows
  prep_y_kernel<<<7456, 256, 0, stream>>>(x, yb, ysq);   // 119,296 rows
  gauss_gemm_kernel<<<3728, 256, 0, stream>>>(yb, ysq, wb, wsq, out);
}

// Round 5
// 308.519 us; speedup vs baseline: 1.3043x; 1.1033x over previous
//
#include <hip/hip_runtime.h>

typedef unsigned short u16;
typedef short short8 __attribute__((ext_vector_type(8)));
typedef float f32x4 __attribute__((ext_vector_type(4)));

#define P_OUT 29791      // 31^3
#define PPAD  29824      // 233*128
#define NBAT  4
#define NCH   512
#define KDIM  128

// ---- fp32 -> bf16 (RNE) ----
__device__ __forceinline__ u16 f2bf(float f) {
  unsigned u = __builtin_bit_cast(unsigned, f);
  unsigned r = (u + 0x7fffu + ((u >> 16) & 1u)) >> 16;
  return (u16)r;
}
__device__ __forceinline__ unsigned pk2(float a, float b) {
  return (unsigned)f2bf(a) | ((unsigned)f2bf(b) << 16);
}

// ---- fused prep ----
// blocks [0, 3844): y-prep, one block per (nb, d, h): stage x slab
//   [16c][2dd][2hh][32w] (8 KB) in LDS coalesced, pack 31 yb rows + ysq.
// blocks [3844, 3876): w-prep (512 rows, 16 rows/block).
__global__ void prep_kernel(const float* __restrict__ x,
                            const float* __restrict__ w,
                            u16* __restrict__ yb, float* __restrict__ ysq,
                            u16* __restrict__ wb, float* __restrict__ wsq) {
  const int tid = threadIdx.x;
  const int b = blockIdx.x;
  if (b >= 3844) {   // ---- w-prep ----
    const int g = (b - 3844) * 16 + (tid >> 4);  // 0..511
    const int c = tid & 15;
    const float4* wr = (const float4*)(w + g * 128 + c * 8);
    float4 f0 = wr[0], f1 = wr[1];
    float s = f0.x*f0.x + f0.y*f0.y + f0.z*f0.z + f0.w*f0.w
            + f1.x*f1.x + f1.y*f1.y + f1.z*f1.z + f1.w*f1.w;
#pragma unroll
    for (int m = 1; m < 16; m <<= 1) s += __shfl_xor(s, m, 64);
    uint4 pk;
    pk.x = pk2(f0.x, f0.y); pk.y = pk2(f0.z, f0.w);
    pk.z = pk2(f1.x, f1.y); pk.w = pk2(f1.z, f1.w);
    *(uint4*)(wb + g * 128 + c * 8) = pk;
    if (c == 0) wsq[g] = s;
    return;
  }
  // ---- y-prep ----
  __shared__ float xs[16][4][33];   // [c][r=kd*2+kh][w], +1 pad -> 2-way max
  const int nb = b / 961;
  const int rem = b - nb * 961;
  const int d = rem / 31;
  const int h = rem - d * 31;
  const float* xb = x + ((size_t)nb << 19) + d * 1024 + h * 32;
  // load 2048 floats, fully coalesced (contiguous 128 B per (c,r))
#pragma unroll
  for (int t = 0; t < 8; ++t) {
    const int e = tid + 256 * t;
    const int c = e >> 7;
    const int r = (e >> 5) & 3;
    const int wv = e & 31;
    xs[c][r][wv] = xb[((size_t)c << 15) + (r >> 1) * 1024 + (r & 1) * 32 + wv];
  }
  __syncthreads();
  const int cs = tid & 15;    // channel = k-chunk of 8
  const int wv0 = tid >> 4;
#pragma unroll
  for (int round = 0; round < 2; ++round) {
    const int wv = wv0 + 16 * round;
    if (wv <= 30) {           // uniform per 16-lane group
      const float v0 = xs[cs][0][wv], v1 = xs[cs][0][wv + 1];
      const float v2 = xs[cs][1][wv], v3 = xs[cs][1][wv + 1];
      const float v4 = xs[cs][2][wv], v5 = xs[cs][2][wv + 1];
      const float v6 = xs[cs][3][wv], v7 = xs[cs][3][wv + 1];
      float s = v0*v0 + v1*v1 + v2*v2 + v3*v3 + v4*v4 + v5*v5 + v6*v6 + v7*v7;
#pragma unroll
      for (int m = 1; m < 16; m <<= 1) s += __shfl_xor(s, m, 64);
      const int g = nb * PPAD + d * 961 + h * 31 + wv;
      uint4 pk;
      pk.x = pk2(v0, v1); pk.y = pk2(v2, v3);
      pk.z = pk2(v4, v5); pk.w = pk2(v6, v7);
      *(uint4*)(yb + (size_t)g * 128 + cs * 8) = pk;
      if (cs == 0) ysq[g] = s;
    }
  }
}

// async global->LDS, 16 B per lane, lands at ldsbase + lane*16
#define GLDS(g, l) __builtin_amdgcn_global_load_lds(                         \
    (const __attribute__((address_space(1))) unsigned int*)(g),              \
    (__attribute__((address_space(3))) unsigned int*)(l), 16, 0, 0)

// ---- GEMM + epilogue: out[n][ch][p] = exp(-(ysq[p] - 2*y.w + wsq[ch])) ----
// (byte-identical to round-1 structure: A = w (m=ch), B = y (n=p), C cols
// contiguous p -> 64 B store segments; XOR-swizzled LDS, conflict-free.)
__global__ void gauss_gemm_kernel(const u16* __restrict__ yb,
                                  const float* __restrict__ ysq,
                                  const u16* __restrict__ wb,
                                  const float* __restrict__ wsq,
                                  float* __restrict__ out) {
  __shared__ __align__(16) u16 As[128 * 64];  // w tile  [ch][k]
  __shared__ __align__(16) u16 Bs[128 * 64];  // y tile  [p][k]

  const int bid = blockIdx.x;
  const int ct = bid & 3;            // 4 ch tiles
  const int pt = (bid >> 2) % 233;   // 233 p tiles
  const int nb = bid / 932;          // 4 batches
  const int p0 = pt * 128;
  const int c0 = ct * 128;

  const int tid = threadIdx.x;
  const int wid = tid >> 6;
  const int lane = tid & 63;
  const int quad = lane >> 4;
  const int col = lane & 15;
  const int wch = wid & 1;   // wave ch-half
  const int wp = wid >> 1;   // wave p-half

  const size_t ybase = ((size_t)nb * PPAD + p0) * 128;

  f32x4 acc[4][4];
#pragma unroll
  for (int i = 0; i < 4; ++i)
#pragma unroll
    for (int j = 0; j < 4; ++j) acc[i][j] = (f32x4){0.f, 0.f, 0.f, 0.f};

#pragma unroll
  for (int it = 0; it < 2; ++it) {
    const int k0 = it * 64;
#pragma unroll
    for (int t = 0; t < 4; ++t) {
      const int Lb = (wid * 4 + t) * 64;      // chunk base (wave-uniform)
      const int L = Lb + lane;
      const int row = L >> 3;
      const int jc = (L & 7) ^ (row & 7);     // unswizzled k-chunk
      GLDS(wb + (size_t)(c0 + row) * 128 + k0 + jc * 8, &As[Lb * 8]);
      GLDS(yb + ybase + (size_t)row * 128 + k0 + jc * 8, &Bs[Lb * 8]);
    }
    __syncthreads();
#pragma unroll
    for (int ks = 0; ks < 2; ++ks) {
      short8 a[4], b[4];
#pragma unroll
      for (int i = 0; i < 4; ++i) {
        const int rowA = wch * 64 + i * 16 + col;
        const int ca = (ks * 4 + quad) ^ (rowA & 7);
        a[i] = *(const short8*)&As[rowA * 64 + ca * 8];
        const int rowB = wp * 64 + i * 16 + col;
        const int cb = (ks * 4 + quad) ^ (rowB & 7);
        b[i] = *(const short8*)&Bs[rowB * 64 + cb * 8];
      }
#pragma unroll
      for (int i = 0; i < 4; ++i)
#pragma unroll
        for (int j = 0; j < 4; ++j)
          acc[i][j] = __builtin_amdgcn_mfma_f32_16x16x32_bf16(a[i], b[j],
                                                              acc[i][j], 0, 0, 0);
    }
    __syncthreads();
  }

  // epilogue: dist = ysq - 2*cross + wsq ; out = exp(-dist)
  float ysv[4];
  int pj[4];
#pragma unroll
  for (int j = 0; j < 4; ++j) {
    pj[j] = p0 + wp * 64 + j * 16 + col;
    ysv[j] = ysq[(size_t)nb * PPAD + pj[j]];
  }
#pragma unroll
  for (int i = 0; i < 4; ++i) {
#pragma unroll
    for (int r = 0; r < 4; ++r) {
      const int ch = c0 + wch * 64 + i * 16 + quad * 4 + r;
      const float wsv = wsq[ch];
      float* ob = out + ((size_t)(nb * NCH + ch)) * P_OUT;
#pragma unroll
      for (int j = 0; j < 4; ++j) {
        if (pj[j] < P_OUT) {
          const float dist = ysv[j] - 2.f * acc[i][j][r] + wsv;
          ob[pj[j]] = __expf(-dist);
        }
      }
    }
  }
}

extern "C" void kernel_launch(void* const* d_in, const int* in_sizes, int n_in,
                              void* d_out, int out_size, void* d_ws, size_t ws_size,
                              hipStream_t stream) {
  const float* x = (const float*)d_in[0];
  const float* w = (const float*)d_in[1];
  float* out = (float*)d_out;
  char* ws = (char*)d_ws;
  // workspace layout (16B-aligned):
  u16* yb    = (u16*)ws;                     // 4*29824*128 bf16 = 61,079,552 B
  float* ysq = (float*)(ws + 61079552);      // 119,296 * 4     =    477,184 B
  u16* wb    = (u16*)(ws + 61556736);        // 512*128 bf16    =    131,072 B
  float* wsq = (float*)(ws + 61687808);      // 512*4           =      2,048 B

  prep_kernel<<<3876, 256, 0, stream>>>(x, w, yb, ysq, wb, wsq);
  gauss_gemm_kernel<<<3728, 256, 0, stream>>>(yb, ysq, wb, wsq, out);
}

// Round 6
// 289.236 us; speedup vs baseline: 1.3912x; 1.0667x over previous
//
#include <hip/hip_runtime.h>

typedef unsigned short u16;
typedef unsigned char u8;
typedef float f32x4 __attribute__((ext_vector_type(4)));

#define P_OUT 29791      // 31^3
#define PPAD  29824      // 233*128
#define NBAT  4
#define NCH   512
#define KDIM  128

// ---- pack 4 fp32 -> 4 fp8 e4m3 (RNE, OCP) ----
__device__ __forceinline__ unsigned pk4_fp8(float a, float b, float c, float d) {
  int v = __builtin_amdgcn_cvt_pk_fp8_f32(a, b, 0, false);   // low word
  v = __builtin_amdgcn_cvt_pk_fp8_f32(c, d, v, true);        // high word
  return (unsigned)v;
}

// ---- fused prep ----
// blocks [0, 3844): y-prep, one block per (nb, d, h): stage x slab
//   [16c][2dd][2hh][32w] (8 KB) in LDS coalesced, pack 31 fp8 rows + ysq.
// blocks [3844, 3876): w-prep (512 rows, 16 rows/block).
__global__ void prep_kernel(const float* __restrict__ x,
                            const float* __restrict__ w,
                            u8* __restrict__ yb, float* __restrict__ ysq,
                            u8* __restrict__ wb, float* __restrict__ wsq) {
  const int tid = threadIdx.x;
  const int b = blockIdx.x;
  if (b >= 3844) {   // ---- w-prep ----
    const int g = (b - 3844) * 16 + (tid >> 4);  // 0..511
    const int c = tid & 15;
    const float4* wr = (const float4*)(w + g * 128 + c * 8);
    float4 f0 = wr[0], f1 = wr[1];
    float s = f0.x*f0.x + f0.y*f0.y + f0.z*f0.z + f0.w*f0.w
            + f1.x*f1.x + f1.y*f1.y + f1.z*f1.z + f1.w*f1.w;
#pragma unroll
    for (int m = 1; m < 16; m <<= 1) s += __shfl_xor(s, m, 64);
    uint2 pk;
    pk.x = pk4_fp8(f0.x, f0.y, f0.z, f0.w);
    pk.y = pk4_fp8(f1.x, f1.y, f1.z, f1.w);
    *(uint2*)(wb + g * 128 + c * 8) = pk;
    if (c == 0) wsq[g] = s;
    return;
  }
  // ---- y-prep ----
  __shared__ float xs[16][4][33];   // [c][r=kd*2+kh][w], +1 pad -> 2-way max
  const int nb = b / 961;
  const int rem = b - nb * 961;
  const int d = rem / 31;
  const int h = rem - d * 31;
  const float* xb = x + ((size_t)nb << 19) + d * 1024 + h * 32;
  // load 2048 floats, fully coalesced (contiguous 128 B per (c,r))
#pragma unroll
  for (int t = 0; t < 8; ++t) {
    const int e = tid + 256 * t;
    const int c = e >> 7;
    const int r = (e >> 5) & 3;
    const int wv = e & 31;
    xs[c][r][wv] = xb[((size_t)c << 15) + (r >> 1) * 1024 + (r & 1) * 32 + wv];
  }
  __syncthreads();
  const int cs = tid & 15;    // channel = k-chunk of 8
  const int wv0 = tid >> 4;
#pragma unroll
  for (int round = 0; round < 2; ++round) {
    const int wv = wv0 + 16 * round;
    if (wv <= 30) {           // uniform per 16-lane group
      const float v0 = xs[cs][0][wv], v1 = xs[cs][0][wv + 1];
      const float v2 = xs[cs][1][wv], v3 = xs[cs][1][wv + 1];
      const float v4 = xs[cs][2][wv], v5 = xs[cs][2][wv + 1];
      const float v6 = xs[cs][3][wv], v7 = xs[cs][3][wv + 1];
      float s = v0*v0 + v1*v1 + v2*v2 + v3*v3 + v4*v4 + v5*v5 + v6*v6 + v7*v7;
#pragma unroll
      for (int m = 1; m < 16; m <<= 1) s += __shfl_xor(s, m, 64);
      const int g = nb * PPAD + d * 961 + h * 31 + wv;
      uint2 pk;
      pk.x = pk4_fp8(v0, v1, v2, v3);
      pk.y = pk4_fp8(v4, v5, v6, v7);
      *(uint2*)(yb + (size_t)g * 128 + cs * 8) = pk;
      if (cs == 0) ysq[g] = s;
    }
  }
}

// async global->LDS, 16 B per lane, lands at ldsbase + lane*16
#define GLDS(g, l) __builtin_amdgcn_global_load_lds(                         \
    (const __attribute__((address_space(1))) unsigned int*)(g),              \
    (__attribute__((address_space(3))) unsigned int*)(l), 16, 0, 0)

// ---- GEMM + epilogue: out[n][ch][p] = exp(-(ysq[p] - 2*y.w + wsq[ch])) ----
// fp8 e4m3 operands: full K=128 staged in ONE 32 KB LDS stage (16 KB w-tile
// + 16 KB y-tile), single barrier, 4 ks-steps of mfma_f32_16x16x32_fp8_fp8.
// Roles as in the verified bf16 version: A = w (m=ch), B = y (n=p); C/D is
// dtype-independent -> col(lane&15)=p contiguous, 64 B store segments.
// LDS: [row][8 chunks of 16 B], chunk pos = chunk ^ (row&7): lane-linear
// staging; b64 frag reads land uniform 4 dwords/bank (= 512 B/instr min).
__global__ void gauss_gemm_kernel(const u8* __restrict__ yb,
                                  const float* __restrict__ ysq,
                                  const u8* __restrict__ wb,
                                  const float* __restrict__ wsq,
                                  float* __restrict__ out) {
  __shared__ __align__(16) u8 Ws[128 * 128];  // w tile [ch][k], 16 KB
  __shared__ __align__(16) u8 Ys[128 * 128];  // y tile [p][k],  16 KB

  const int bid = blockIdx.x;
  const int ct = bid & 3;            // 4 ch tiles
  const int pt = (bid >> 2) % 233;   // 233 p tiles
  const int nb = bid / 932;          // 4 batches
  const int p0 = pt * 128;
  const int c0 = ct * 128;

  const int tid = threadIdx.x;
  const int wid = tid >> 6;
  const int lane = tid & 63;
  const int quad = lane >> 4;
  const int col = lane & 15;
  const int wch = wid & 1;   // wave ch-half
  const int wp = wid >> 1;   // wave p-half

  const size_t ybase = ((size_t)nb * PPAD + p0) * 128;   // bytes

  // ---- stage full K: 1024 chunks of 16 B per tile, 4 rounds each ----
#pragma unroll
  for (int t = 0; t < 4; ++t) {
    const int Lb = (wid * 4 + t) * 64;      // chunk base (wave-uniform)
    const int L = Lb + lane;
    const int row = L >> 3;                 // 8 chunks per 128 B row
    const int jc = (L & 7) ^ (row & 7);     // unswizzled 16B k-chunk
    GLDS(wb + (size_t)(c0 + row) * 128 + jc * 16, &Ws[Lb * 16]);
    GLDS(yb + ybase + (size_t)row * 128 + jc * 16, &Ys[Lb * 16]);
  }

  f32x4 acc[4][4];
#pragma unroll
  for (int i = 0; i < 4; ++i)
#pragma unroll
    for (int j = 0; j < 4; ++j) acc[i][j] = (f32x4){0.f, 0.f, 0.f, 0.f};

  __syncthreads();   // drains GLDS (vmcnt) + all lanes ready

  const int c16b = quad >> 1;   // lane's 16B-chunk offset within ks window
  const int hoff = (quad & 1) * 8;
#pragma unroll
  for (int ks = 0; ks < 4; ++ks) {
    long long a[4], b[4];
#pragma unroll
    for (int i = 0; i < 4; ++i) {
      const int rowA = wch * 64 + i * 16 + col;
      const int pa = (ks * 2 + c16b) ^ (rowA & 7);
      a[i] = *(const long long*)&Ws[rowA * 128 + pa * 16 + hoff];
      const int rowB = wp * 64 + i * 16 + col;
      const int pb = (ks * 2 + c16b) ^ (rowB & 7);
      b[i] = *(const long long*)&Ys[rowB * 128 + pb * 16 + hoff];
    }
#pragma unroll
    for (int i = 0; i < 4; ++i)
#pragma unroll
      for (int j = 0; j < 4; ++j)
        acc[i][j] = __builtin_amdgcn_mfma_f32_16x16x32_fp8_fp8(a[i], b[j],
                                                               acc[i][j], 0, 0, 0);
  }
  // no trailing barrier: stores below are fire-and-forget to kernel end

  // epilogue: dist = ysq - 2*cross + wsq ; out = exp(-dist)
  float ysv[4];
  int pj[4];
#pragma unroll
  for (int j = 0; j < 4; ++j) {
    pj[j] = p0 + wp * 64 + j * 16 + col;
    ysv[j] = ysq[(size_t)nb * PPAD + pj[j]];
  }
#pragma unroll
  for (int i = 0; i < 4; ++i) {
#pragma unroll
    for (int r = 0; r < 4; ++r) {
      const int ch = c0 + wch * 64 + i * 16 + quad * 4 + r;
      const float wsv = wsq[ch];
      float* ob = out + ((size_t)(nb * NCH + ch)) * P_OUT;
#pragma unroll
      for (int j = 0; j < 4; ++j) {
        if (pj[j] < P_OUT) {
          const float dist = ysv[j] - 2.f * acc[i][j][r] + wsv;
          ob[pj[j]] = __expf(-dist);
        }
      }
    }
  }
}

extern "C" void kernel_launch(void* const* d_in, const int* in_sizes, int n_in,
                              void* d_out, int out_size, void* d_ws, size_t ws_size,
                              hipStream_t stream) {
  const float* x = (const float*)d_in[0];
  const float* w = (const float*)d_in[1];
  float* out = (float*)d_out;
  char* ws = (char*)d_ws;
  // workspace layout (128B-aligned):
  u8* yb     = (u8*)ws;                      // 4*29824*128 fp8 = 15,269,888 B
  float* ysq = (float*)(ws + 15269888);      // 119,296 * 4     =    477,184 B
  u8* wb     = (u8*)(ws + 15747072);         // 512*128 fp8     =     65,536 B
  float* wsq = (float*)(ws + 15812608);      // 512*4           =      2,048 B

  prep_kernel<<<3876, 256, 0, stream>>>(x, w, yb, ysq, wb, wsq);
  gauss_gemm_kernel<<<3728, 256, 0, stream>>>(yb, ysq, wb, wsq, out);
}